// Round 8
// baseline (2626.678 us; speedup 1.0000x reference)
//
#include <hip/hip_runtime.h>
#include <hip/hip_bf16.h>

#define L_NUM 20
#define CC 128
#define TB 8192
#define BB 8
#define TT 64
#define NM (128 * 128)

#define NCONV (L_NUM * 3 * 256 * 128)
#define XN    ((size_t)BB * TB * CC)   // elements per bf16 x plane

typedef __attribute__((ext_vector_type(4))) float f32x4;
typedef __attribute__((ext_vector_type(8))) short bf16x8;
typedef unsigned int u32;

#define MFMA16 __builtin_amdgcn_mfma_f32_16x16x32_bf16

static const int DILS[L_NUM] = {1, 2, 4, 8, 16, 32, 64, 128, 256, 512,
                                1, 2, 4, 8, 16, 32, 64, 128, 256, 512};

__device__ __forceinline__ unsigned short f2b(float f) {
  union { __hip_bfloat16 h; unsigned short u; } cv;
  cv.h = __float2bfloat16(f);
  return cv.u;
}
__device__ __forceinline__ float b2fu(u32 u) {
  union { u32 u; float f; } cv;
  cv.u = u << 16;
  return cv.f;
}

// byte offset into a [64 t][128 c] bf16 LDS tile, XOR-swizzled (G4)
__device__ __forceinline__ int swz(int t, int cbyte) {
  return (t * 256 + cbyte) ^ ((t & 7) << 4);
}

// async global->LDS, 16B per lane; LDS dest = wave-uniform base + lane*16
__device__ __forceinline__ void gload16(const void* g, void* l) {
  __builtin_amdgcn_global_load_lds(
      (const __attribute__((address_space(1))) u32*)g,
      (__attribute__((address_space(3))) u32*)l, 16, 0, 0);
}

__global__ void prep_kernel(const float* __restrict__ Wconv,
                            const float* __restrict__ Wout,
                            const float* __restrict__ Wskip,
                            unsigned short* __restrict__ wc,
                            unsigned short* __restrict__ wo,
                            unsigned short* __restrict__ wsk,
                            unsigned short* __restrict__ zp) {
  int i = blockIdx.x * 256 + threadIdx.x;
  if (i < 128) zp[i] = 0;
  if (i < NCONV) {
    // dst [l][k][o][c] <- src [l][o][c][k]
    int c = i & 127;
    int o = (i >> 7) & 255;
    int lk = i >> 15;
    int k = lk % 3;
    int l = lk / 3;
    wc[i] = f2b(Wconv[((size_t)(l * 256 + o) * 128 + c) * 3 + k]);
  }
  if (i < L_NUM * NM) {
    wo[i]  = f2b(Wout[i]);
    wsk[i] = f2b(Wskip[i]);
  }
}

// x0 f32 [B][C][T] -> hi/lo bf16 [B][T][C] (plain linear layout)
__global__ __launch_bounds__(256) void x0t_kernel(const float* __restrict__ x0,
                                                  unsigned short* __restrict__ hi,
                                                  unsigned short* __restrict__ lo) {
  __shared__ unsigned short Hs[64 * CC], Ls[64 * CC];
  const int tid = threadIdx.x, lane = tid & 63, w = tid >> 6;
  const int b = blockIdx.y, t0 = blockIdx.x * 64;
  const float* xb = x0 + (size_t)b * CC * TB;
#pragma unroll
  for (int it = 0; it < 8; ++it) {
    int c0 = it * 16 + w * 4;
    u32 hu[4], lu[4];
#pragma unroll
    for (int i2 = 0; i2 < 4; ++i2) {
      float v = xb[(size_t)(c0 + i2) * TB + t0 + lane];
      unsigned short h = f2b(v);
      hu[i2] = h;
      lu[i2] = f2b(v - b2fu(h));
    }
    uint2 hp, lp;
    hp.x = hu[0] | (hu[1] << 16); hp.y = hu[2] | (hu[3] << 16);
    lp.x = lu[0] | (lu[1] << 16); lp.y = lu[2] | (lu[3] << 16);
    *reinterpret_cast<uint2*>(reinterpret_cast<char*>(Hs) + swz(lane, c0 * 2)) = hp;
    *reinterpret_cast<uint2*>(reinterpret_cast<char*>(Ls) + swz(lane, c0 * 2)) = lp;
  }
  __syncthreads();
  unsigned short* hb = hi + ((size_t)b * TB + t0) * CC;
  unsigned short* lb = lo + ((size_t)b * TB + t0) * CC;
#pragma unroll
  for (int it = 0; it < 4; ++it) {
    int o = it * 4096 + tid * 16;
    int t = o >> 8;
    int cl = o & 255;
    int li = t * 256 + (cl ^ ((t & 7) << 4));
    *reinterpret_cast<f32x4*>(reinterpret_cast<char*>(hb) + (size_t)t * 256 + cl) =
        *reinterpret_cast<f32x4*>(reinterpret_cast<char*>(Hs) + li);
    *reinterpret_cast<f32x4*>(reinterpret_cast<char*>(lb) + (size_t)t * 256 + cl) =
        *reinterpret_cast<f32x4*>(reinterpret_cast<char*>(Ls) + li);
  }
}

// One launch per layer step. 2048 blocks: role 0 (conv+act+z+out+resid for layer
// l) and role 1 (skip GEMM + nt stores for layer l-1) interleaved every 8 blocks
// so both roles spread across XCDs and co-schedule — the 671 MB skip stream
// overlaps the conv blocks' latency phases instead of serializing behind them.
// batch == XCD: all tap/z/hi traffic stays in the XCD's own L2.
__global__ __launch_bounds__(256, 4) void step_kernel(
    const unsigned short* __restrict__ hi_in,  // [B][T][C] bf16 x_l hi
    unsigned short* __restrict__ hi_out,       // [B][T][C] bf16 x_{l+1} hi
    unsigned short* __restrict__ lob,          // [B][T][C] bf16 lo (in-place)
    unsigned short* __restrict__ z_out,        // [B][T][C] bf16 z_l
    const unsigned short* __restrict__ z_prev, // [B][T][C] bf16 z_{l-1}
    const unsigned short* __restrict__ zpage,  // 256B zeros
    const unsigned short* __restrict__ Wc,     // [3][256][128] bf16 (layer l)
    const float* __restrict__ bconv,           // [256]
    const unsigned short* __restrict__ Wo,     // [128][128] bf16 (layer l)
    const float* __restrict__ bout,            // [128]
    const unsigned short* __restrict__ Wsk,    // [128][128] bf16 (layer l-1)
    const float* __restrict__ bskip,           // [128]  (layer l-1)
    float* __restrict__ skipo,                 // [B][S][T] f32 (layer l-1 slice)
    float* __restrict__ fxout,                 // [B][C][T] f32 (l==19 only)
    int dil, int do_conv, int do_skip, int last) {
  __shared__ unsigned short Xs[2][TT * CC];   // taps 0,1 (32 KB); z overlays Xs[0]

  const int tid = threadIdx.x;
  const int lane = tid & 63;
  const int w = tid >> 6;
  const int lo16 = lane & 15;
  const int hi4 = lane >> 4;

  const int p = blockIdx.x;          // 0..2047
  const int xcd = p & 7;
  const int role = (p >> 3) & 1;
  const int idx = p >> 4;            // 0..127 tile index
  const int b = xcd;                 // batch == XCD
  const int t0 = idx * TT;
  const int cB = w * 32 + hi4 * 4;   // base channel for r=0 (r adds 16)

  f32x4 zero4 = {0.f, 0.f, 0.f, 0.f};

  if (role == 1) {
    // ================= skip GEMM of layer l-1 (streaming, no LDS) =============
    if (!do_skip) return;
    const unsigned short* zb = z_prev + (size_t)b * TB * CC;
    float* skb = skipo + (size_t)b * CC * TB;

    f32x4 accS[2][4];
#pragma unroll
    for (int r = 0; r < 2; ++r)
#pragma unroll
      for (int j = 0; j < 4; ++j) accS[r][j] = zero4;

#pragma unroll
    for (int kk = 0; kk < 4; ++kk) {
      int c0 = kk * 32 + hi4 * 8;
      bf16x8 aS0 = *reinterpret_cast<const bf16x8*>(Wsk + (w * 32 + lo16) * 128 + c0);
      bf16x8 aS1 = *reinterpret_cast<const bf16x8*>(Wsk + (w * 32 + 16 + lo16) * 128 + c0);
#pragma unroll
      for (int j = 0; j < 4; ++j) {
        bf16x8 bz = *reinterpret_cast<const bf16x8*>(
            zb + (size_t)(t0 + j * 16 + lo16) * CC + c0);
        accS[0][j] = MFMA16(aS0, bz, accS[0][j], 0, 0, 0);
        accS[1][j] = MFMA16(aS1, bz, accS[1][j], 0, 0, 0);
      }
    }
#pragma unroll
    for (int r = 0; r < 2; ++r) {
      f32x4 bsk = *reinterpret_cast<const f32x4*>(bskip + cB + r * 16);
#pragma unroll
      for (int j = 0; j < 4; ++j) {
        int t = j * 16 + lo16;
#pragma unroll
        for (int reg = 0; reg < 4; ++reg)
          __builtin_nontemporal_store(accS[r][j][reg] + bsk[reg],
                                      skb + (size_t)(cB + r * 16 + reg) * TB + t0 + t);
      }
    }
    return;
  }

  // =================== conv role: layer l ====================================
  if (!do_conv) return;
  const unsigned short* hb = hi_in + (size_t)b * TB * CC;

  // stage taps 0,1 via global_load_lds (linear LDS, pre-swizzled source)
#pragma unroll
  for (int k = 0; k < 2; ++k) {
    int tbase = t0 + (k - 2) * dil;
#pragma unroll
    for (int i = 0; i < 4; ++i) {
      int o = w * 4096 + i * 1024 + lane * 16;
      int tl = o >> 8;
      int cb = (o & 255) ^ ((tl & 7) << 4);
      int tg = tbase + tl;
      const char* src = (tg >= 0)
          ? (reinterpret_cast<const char*>(hb + (size_t)tg * CC) + cb)
          : (reinterpret_cast<const char*>(zpage) + cb);
      gload16(src, reinterpret_cast<char*>(&Xs[k][0]) + o);
    }
  }

  f32x4 accA[2][4], accG[2][4];
#pragma unroll
  for (int r = 0; r < 2; ++r)
#pragma unroll
    for (int j = 0; j < 4; ++j) { accA[r][j] = zero4; accG[r][j] = zero4; }

  // tap 2: B-frags direct from global (own window, L2-hot)
  {
    const unsigned short* Wk = Wc + 2 * 256 * 128;
#pragma unroll
    for (int kk = 0; kk < 4; ++kk) {
      int c0 = kk * 32 + hi4 * 8;
      bf16x8 aA0 = *reinterpret_cast<const bf16x8*>(Wk + (w * 32 + lo16) * 128 + c0);
      bf16x8 aA1 = *reinterpret_cast<const bf16x8*>(Wk + (w * 32 + 16 + lo16) * 128 + c0);
      bf16x8 aG0 = *reinterpret_cast<const bf16x8*>(Wk + (128 + w * 32 + lo16) * 128 + c0);
      bf16x8 aG1 = *reinterpret_cast<const bf16x8*>(Wk + (128 + w * 32 + 16 + lo16) * 128 + c0);
#pragma unroll
      for (int j = 0; j < 4; ++j) {
        bf16x8 bx8 = *reinterpret_cast<const bf16x8*>(
            hb + (size_t)(t0 + j * 16 + lo16) * CC + c0);
        accA[0][j] = MFMA16(aA0, bx8, accA[0][j], 0, 0, 0);
        accA[1][j] = MFMA16(aA1, bx8, accA[1][j], 0, 0, 0);
        accG[0][j] = MFMA16(aG0, bx8, accG[0][j], 0, 0, 0);
        accG[1][j] = MFMA16(aG1, bx8, accG[1][j], 0, 0, 0);
      }
    }
  }

  // residual hi/lo prefetch (consumed in epilogue)
  const unsigned short* lb = lob + (size_t)b * TB * CC;
  uint2 hres[2][4], lres[2][4];
#pragma unroll
  for (int r = 0; r < 2; ++r)
#pragma unroll
    for (int j = 0; j < 4; ++j) {
      int t = t0 + j * 16 + lo16;
      hres[r][j] = *reinterpret_cast<const uint2*>(hb + (size_t)t * CC + cB + r * 16);
      lres[r][j] = *reinterpret_cast<const uint2*>(lb + (size_t)t * CC + cB + r * 16);
    }

  __syncthreads();  // bar1: taps 0,1 resident

#pragma unroll
  for (int k = 0; k < 2; ++k) {
    const unsigned short* Wk = Wc + k * 256 * 128;
#pragma unroll
    for (int kk = 0; kk < 4; ++kk) {
      int c0 = kk * 32 + hi4 * 8;
      bf16x8 aA0 = *reinterpret_cast<const bf16x8*>(Wk + (w * 32 + lo16) * 128 + c0);
      bf16x8 aA1 = *reinterpret_cast<const bf16x8*>(Wk + (w * 32 + 16 + lo16) * 128 + c0);
      bf16x8 aG0 = *reinterpret_cast<const bf16x8*>(Wk + (128 + w * 32 + lo16) * 128 + c0);
      bf16x8 aG1 = *reinterpret_cast<const bf16x8*>(Wk + (128 + w * 32 + 16 + lo16) * 128 + c0);
#pragma unroll
      for (int j = 0; j < 4; ++j) {
        bf16x8 bx8 = *reinterpret_cast<const bf16x8*>(
            reinterpret_cast<const char*>(&Xs[k][0]) + swz(j * 16 + lo16, c0 * 2));
        accA[0][j] = MFMA16(aA0, bx8, accA[0][j], 0, 0, 0);
        accA[1][j] = MFMA16(aA1, bx8, accA[1][j], 0, 0, 0);
        accG[0][j] = MFMA16(aG0, bx8, accG[0][j], 0, 0, 0);
        accG[1][j] = MFMA16(aG1, bx8, accG[1][j], 0, 0, 0);
      }
    }
  }

  // gated activation -> zpk registers
  uint2 zpk[2][4];
#pragma unroll
  for (int r = 0; r < 2; ++r) {
    f32x4 bca = *reinterpret_cast<const f32x4*>(bconv + cB + r * 16);
    f32x4 bcg = *reinterpret_cast<const f32x4*>(bconv + 128 + cB + r * 16);
#pragma unroll
    for (int j = 0; j < 4; ++j) {
      u32 zu[4];
#pragma unroll
      for (int reg = 0; reg < 4; ++reg) {
        float a = accA[r][j][reg] + bca[reg];
        float g = accG[r][j][reg] + bcg[reg];
        float ea = __builtin_amdgcn_exp2f(2.885390081777927f * a);   // e^{2a}
        float th = 1.f - 2.f * __builtin_amdgcn_rcpf(1.f + ea);       // tanh(a)
        float sg = __builtin_amdgcn_rcpf(
            1.f + __builtin_amdgcn_exp2f(-1.4426950408889634f * g));  // sigmoid
        zu[reg] = f2b(th * sg);
      }
      zpk[r][j].x = zu[0] | (zu[1] << 16);
      zpk[r][j].y = zu[2] | (zu[3] << 16);
    }
  }

  __syncthreads();  // bar2: all GEMM1 tap0 reads complete

  // z -> LDS (overlay tap0, swizzled)
#pragma unroll
  for (int r = 0; r < 2; ++r)
#pragma unroll
    for (int j = 0; j < 4; ++j)
      *reinterpret_cast<uint2*>(reinterpret_cast<char*>(&Xs[0][0]) +
          swz(j * 16 + lo16, (cB + r * 16) * 2)) = zpk[r][j];
  __syncthreads();  // bar3: z tile complete

  // z copy-out LDS -> global plane (coalesced 16B; read by next launch's skips)
  {
    unsigned short* zb = z_out + ((size_t)b * TB + t0) * CC;
#pragma unroll
    for (int it = 0; it < 4; ++it) {
      int o = it * 4096 + tid * 16;
      int t = o >> 8;
      int cl = o & 255;
      int li = t * 256 + (cl ^ ((t & 7) << 4));
      *reinterpret_cast<f32x4*>(reinterpret_cast<char*>(zb) + (size_t)t * 256 + cl) =
          *reinterpret_cast<f32x4*>(reinterpret_cast<char*>(&Xs[0][0]) + li);
    }
  }

  if (!last) {
    // out GEMM from LDS z
    f32x4 accO[2][4];
#pragma unroll
    for (int r = 0; r < 2; ++r)
#pragma unroll
      for (int j = 0; j < 4; ++j) accO[r][j] = zero4;

#pragma unroll
    for (int kk = 0; kk < 4; ++kk) {
      int c0 = kk * 32 + hi4 * 8;
      bf16x8 aO0 = *reinterpret_cast<const bf16x8*>(Wo + (w * 32 + lo16) * 128 + c0);
      bf16x8 aO1 = *reinterpret_cast<const bf16x8*>(Wo + (w * 32 + 16 + lo16) * 128 + c0);
#pragma unroll
      for (int j = 0; j < 4; ++j) {
        bf16x8 bz = *reinterpret_cast<const bf16x8*>(
            reinterpret_cast<const char*>(&Xs[0][0]) + swz(j * 16 + lo16, c0 * 2));
        accO[0][j] = MFMA16(aO0, bz, accO[0][j], 0, 0, 0);
        accO[1][j] = MFMA16(aO1, bz, accO[1][j], 0, 0, 0);
      }
    }

    unsigned short* hrow = hi_out + (size_t)b * TB * CC;
    unsigned short* lrow = lob + (size_t)b * TB * CC;
#pragma unroll
    for (int r = 0; r < 2; ++r) {
      f32x4 bo = *reinterpret_cast<const f32x4*>(bout + cB + r * 16);
#pragma unroll
      for (int j = 0; j < 4; ++j) {
        int t = t0 + j * 16 + lo16;
        u32 hu[4] = {hres[r][j].x & 0xffffu, hres[r][j].x >> 16,
                     hres[r][j].y & 0xffffu, hres[r][j].y >> 16};
        u32 lu[4] = {lres[r][j].x & 0xffffu, lres[r][j].x >> 16,
                     lres[r][j].y & 0xffffu, lres[r][j].y >> 16};
        u32 hn[4], ln[4];
#pragma unroll
        for (int reg = 0; reg < 4; ++reg) {
          float v = accO[r][j][reg] + bo[reg] + b2fu(hu[reg]) + b2fu(lu[reg]);
          unsigned short h = f2b(v);
          hn[reg] = h;
          ln[reg] = f2b(v - b2fu(h));
        }
        uint2 hq, lq;
        hq.x = hn[0] | (hn[1] << 16); hq.y = hn[2] | (hn[3] << 16);
        lq.x = ln[0] | (ln[1] << 16); lq.y = ln[2] | (ln[3] << 16);
        *reinterpret_cast<uint2*>(hrow + (size_t)t * CC + cB + r * 16) = hq;
        *reinterpret_cast<uint2*>(lrow + (size_t)t * CC + cB + r * 16) = lq;
      }
    }
  } else {
    // final layer: fx = z + hi + lo (f32, [B][C][T]), straight from registers
    float* fxb = fxout + (size_t)b * CC * TB;
#pragma unroll
    for (int r = 0; r < 2; ++r) {
#pragma unroll
      for (int j = 0; j < 4; ++j) {
        int t = j * 16 + lo16;
        u32 zu[4] = {zpk[r][j].x & 0xffffu, zpk[r][j].x >> 16,
                     zpk[r][j].y & 0xffffu, zpk[r][j].y >> 16};
        u32 hu[4] = {hres[r][j].x & 0xffffu, hres[r][j].x >> 16,
                     hres[r][j].y & 0xffffu, hres[r][j].y >> 16};
        u32 lu[4] = {lres[r][j].x & 0xffffu, lres[r][j].x >> 16,
                     lres[r][j].y & 0xffffu, lres[r][j].y >> 16};
#pragma unroll
        for (int reg = 0; reg < 4; ++reg)
          __builtin_nontemporal_store(
              b2fu(zu[reg]) + b2fu(hu[reg]) + b2fu(lu[reg]),
              fxb + (size_t)(cB + r * 16 + reg) * TB + t0 + t);
      }
    }
  }
}

extern "C" void kernel_launch(void* const* d_in, const int* in_sizes, int n_in,
                              void* d_out, int out_size, void* d_ws, size_t ws_size,
                              hipStream_t stream) {
  const float* x0    = (const float*)d_in[0];
  const float* Wconv = (const float*)d_in[1];
  const float* bconv = (const float*)d_in[2];
  const float* Wout  = (const float*)d_in[3];
  const float* bout  = (const float*)d_in[4];
  const float* Wskip = (const float*)d_in[5];
  const float* bskip = (const float*)d_in[6];

  unsigned short* wc  = (unsigned short*)d_ws;   // [L][3][256][128] bf16
  unsigned short* wo  = wc + NCONV;              // [L][128][128] bf16
  unsigned short* wsk = wo + L_NUM * NM;         // [L][128][128] bf16
  unsigned short* zp  = wsk + L_NUM * NM;        // 256B zero page
  unsigned short* hi1 = zp + 128;                // hi plane (parity 1)
  unsigned short* lo  = hi1 + XN;                // lo plane (in-place)
  unsigned short* zP0 = lo + XN;                 // z plane parity 0
  unsigned short* zP1 = zP0 + XN;                // z plane parity 1
  // ws total ~= 72.5 MB

  float* fx = (float*)d_out;                      // final x [B][C][T] f32
  float* skips = fx + XN;                         // [L][B][S][T] f32
  unsigned short* hi0 = (unsigned short*)d_out;   // hi plane parity 0, aliased in
  // fx region: hi0 last READ at l=18; l=19 overwrites the region with f32 fx.

  unsigned short* hiP[2] = {hi0, hi1};
  unsigned short* zPP[2] = {zP0, zP1};

  prep_kernel<<<(NCONV + 255) / 256, 256, 0, stream>>>(Wconv, Wout, Wskip, wc, wo, wsk, zp);
  x0t_kernel<<<dim3(TB / 64, BB), 256, 0, stream>>>(x0, hiP[0], lo);

  for (int l = 0; l <= L_NUM; ++l) {
    int cl = l < L_NUM ? l : L_NUM - 1;   // conv layer index (guarded by do_conv)
    int sl = l > 0 ? l - 1 : 0;           // skip layer index (guarded by do_skip)
    step_kernel<<<2048, 256, 0, stream>>>(
        hiP[l & 1], hiP[(l + 1) & 1], lo,
        zPP[l & 1], zPP[(l + 1) & 1], zp,
        wc + (size_t)cl * 3 * 256 * 128, bconv + (size_t)cl * 256,
        wo + (size_t)cl * NM, bout + (size_t)cl * 128,
        wsk + (size_t)sl * NM, bskip + (size_t)sl * 128,
        skips + (size_t)sl * XN, fx,
        DILS[cl], l < L_NUM ? 1 : 0, l > 0 ? 1 : 0,
        l == L_NUM - 1 ? 1 : 0);
  }
}